// Round 6
// baseline (501.228 us; speedup 1.0000x reference)
//
#include <hip/hip_runtime.h>
#include <hip/hip_bf16.h>
#include <stdint.h>

typedef __attribute__((ext_vector_type(4))) float f32x4;
typedef __attribute__((ext_vector_type(16))) float f32x16;
typedef __attribute__((ext_vector_type(8))) short short8;

__device__ __forceinline__ unsigned short f32_to_bf16_rne(float f) {
  union { float f; unsigned int u; } v; v.f = f;
  unsigned int u = v.u;
  unsigned int r = u + 0x7fffu + ((u >> 16) & 1u);
  return (unsigned short)(r >> 16);
}

#define GLOAD16(gp, lp)                                                 \
  __builtin_amdgcn_global_load_lds(                                     \
      (const __attribute__((address_space(1))) void*)(const void*)(gp), \
      (__attribute__((address_space(3))) void*)(void*)(lp), 16, 0, 0)

#define BAR() __builtin_amdgcn_s_barrier()
#define WAIT_LGKM0() asm volatile("s_waitcnt lgkmcnt(0)" ::: "memory")
#define WAIT_VM8() asm volatile("s_waitcnt vmcnt(8)" ::: "memory")
#define WAIT_VM0() asm volatile("s_waitcnt vmcnt(0)" ::: "memory")

// ---------------- merged converter / packer ----------------
// Segments: [0, NX4): x fp32->bf16 ; [NX4, NX4+ND4): down_w ; rest: Bcat pack.
// Bcat[16384][2048]: row R -> grp=R>>6, s=R&63; s<32: gate row grp*32+s,
// else up row grp*32+(s-32).  (32-row interleave: each 32x32 B-frag is pure
// gate or pure up.)
__global__ __launch_bounds__(256) void prep(
    const float* __restrict__ x, const float* __restrict__ g,
    const float* __restrict__ u, const float* __restrict__ dw,
    unsigned short* __restrict__ x_bf, unsigned short* __restrict__ d_bf,
    unsigned short* __restrict__ Bcat) {
  const int NX4 = 2097152;   // 4096*2048/4
  const int ND4 = 4194304;   // 2048*8192/4
  const int NP4 = 8388608;   // 16384*2048/4
  const int total = NX4 + ND4 + NP4;
  int i = blockIdx.x * 256 + threadIdx.x;
  for (; i < total; i += gridDim.x * 256) {
    const float* src;
    unsigned short* dst;
    if (i < NX4) {
      src = x + ((size_t)i << 2);
      dst = x_bf + ((size_t)i << 2);
    } else if (i < NX4 + ND4) {
      int j = i - NX4;
      src = dw + ((size_t)j << 2);
      dst = d_bf + ((size_t)j << 2);
    } else {
      int j = i - NX4 - ND4;
      int R = j >> 9, h4 = j & 511;
      int grp = R >> 6, s = R & 63;
      src = (s < 32 ? g : u) + (((size_t)(grp * 32 + (s & 31))) << 11) + (h4 << 2);
      dst = Bcat + ((size_t)j << 2);
    }
    float4 v = *reinterpret_cast<const float4*>(src);
    ushort4 o;
    o.x = f32_to_bf16_rne(v.x);
    o.y = f32_to_bf16_rne(v.y);
    o.z = f32_to_bf16_rne(v.z);
    o.w = f32_to_bf16_rne(v.w);
    *reinterpret_cast<ushort4*>(dst) = o;
  }
}

__global__ __launch_bounds__(256) void reduce_add(const float* __restrict__ a,
                                                  const float* __restrict__ b,
                                                  float* __restrict__ o, int n4) {
  int i = blockIdx.x * 256 + threadIdx.x;
  for (; i < n4; i += gridDim.x * 256) {
    float4 x = reinterpret_cast<const float4*>(a)[i];
    float4 y = reinterpret_cast<const float4*>(b)[i];
    float4 z;
    z.x = x.x + y.x; z.y = x.y + y.y; z.z = x.z + y.z; z.w = x.w + y.w;
    reinterpret_cast<float4*>(o)[i] = z;
  }
}

// ---------------- 256x256x64 8-phase GEMM, 32x32x16 MFMA ----------------
// C = A(M x K) * B(N x K)^T, bf16 K-major. 8 waves, wave tile 128x64:
// 4 m-frags x 2 n-frags of 32x32, 4 k-steps per BK=64 tile.
// 2-tile-deep prefetch: during tile t stage all of t+2; boundary vmcnt(8)
// retires exactly tile t+1's 8 loads.
// A/B operand layout (32x32x16): lane holds row=ln&31, k=(ln>>5)*8+[0,8).
// C/D layout: col=lane&31, row=(reg&3)+8*(reg>>2)+4*(lane>>5)  [m74/m101].

#define MFMA_P(MH, NH)                                                        \
  do {                                                                        \
    _Pragma("unroll") for (int ks = 0; ks < 4; ++ks) {                        \
      _Pragma("unroll") for (int mp = 0; mp < 2; ++mp) {                      \
        acc[(MH)*2 + mp][NH] = __builtin_amdgcn_mfma_f32_32x32x16_bf16(       \
            a[mp][ks], b[NH][ks], acc[(MH)*2 + mp][NH], 0, 0, 0);             \
      }                                                                       \
    }                                                                         \
  } while (0)

#define STAGE(MAT, BUF, H, T)                                                 \
  do {                                                                        \
    const unsigned short* p0_ =                                               \
        MAT##base + (size_t)((H)*128 + r0) * ld##MAT + (size_t)(T)*64 + c0;   \
    const unsigned short* p1_ =                                               \
        MAT##base + (size_t)((H)*128 + r1) * ld##MAT + (size_t)(T)*64 + c1;   \
    GLOAD16(p0_, &s##MAT[BUF][H][off0 >> 1]);                                 \
    GLOAD16(p1_, &s##MAT[BUF][H][(off0 >> 1) + 512]);                         \
  } while (0)

#define LDA32(dst, BUF, MI, KS)                                               \
  {                                                                           \
    int row_ = (MI)*32 + (ln & 31);                                           \
    int lb_ = row_ * 128 + (KS)*32 + ((ln >> 5) << 4);                        \
    int ph_ = lb_ ^ ((row_ & 7) << 4);                                        \
    dst = *reinterpret_cast<const short8*>(                                   \
        reinterpret_cast<const char*>(&sA[BUF][wr][0]) + ph_);                \
  }

#define LDB32(dst, BUF, NI, KS)                                               \
  {                                                                           \
    int row_ = (wc & 1) * 64 + (NI)*32 + (ln & 31);                           \
    int lb_ = row_ * 128 + (KS)*32 + ((ln >> 5) << 4);                        \
    int ph_ = lb_ ^ ((row_ & 7) << 4);                                        \
    dst = *reinterpret_cast<const short8*>(                                   \
        reinterpret_cast<const char*>(&sB[BUF][wc >> 1][0]) + ph_);           \
  }

template <int EPI>
__global__ __launch_bounds__(512, 2) void gemm8p(
    const unsigned short* __restrict__ A, const unsigned short* __restrict__ B,
    void* __restrict__ Cout, int K, int ldA, int ldB, int Nout, size_t zstride,
    int nbm, int nbn) {
  __shared__ unsigned short sA[2][2][128 * 64];
  __shared__ unsigned short sB[2][2][128 * 64];

  const int t = threadIdx.x;
  const int wv = t >> 6, ln = t & 63;
  const int wr = wv >> 2, wc = wv & 3;

  // bijective XCD swizzle (gridDim.x % 8 == 0)
  const int r = blockIdx.x;
  const int swz = (r & 7) * (gridDim.x >> 3) + (r >> 3);
  const int bm = swz % nbm;
  const int rest = swz / nbm;
  const int bn = rest % nbn;
  const int bz = rest / nbn;

  A += (size_t)bz * K;
  B += (size_t)bz * K;

  const int off0 = wv * 2048 + ln * 16;
  const int off1 = off0 + 1024;
  const int s0 = off0 ^ (((off0 >> 7) & 7) << 4);
  const int s1 = off1 ^ (((off1 >> 7) & 7) << 4);
  const int r0 = s0 >> 7, c0 = (s0 & 127) >> 1;
  const int r1 = s1 >> 7, c1 = (s1 & 127) >> 1;

  const unsigned short* Abase = A + (size_t)(bm * 256) * ldA;
  const unsigned short* Bbase = B + (size_t)(bn * 256) * ldB;

  f32x16 acc[4][2] = {};
  short8 a[2][4], b[2][4];

  const int NT = K >> 6;  // NT >= 2

  // Prologue: tiles 0 and 1 fully staged (16 loads); vmcnt(8) retires tile 0.
  STAGE(A, 0, 0, 0); STAGE(A, 0, 1, 0);
  STAGE(B, 0, 0, 0); STAGE(B, 0, 1, 0);
  STAGE(A, 1, 0, 1); STAGE(A, 1, 1, 1);
  STAGE(B, 1, 0, 1); STAGE(B, 1, 1, 1);
  WAIT_VM8();
  BAR();

  for (int tt = 0; tt < NT; ++tt) {
    const int buf = tt & 1;
    // Phase 0: read m-frags 0,1 (8 reads) + n-frag 0 (4 reads)
#pragma unroll
    for (int mp = 0; mp < 2; ++mp)
#pragma unroll
      for (int ks = 0; ks < 4; ++ks) LDA32(a[mp][ks], buf, mp, ks);
#pragma unroll
    for (int ks = 0; ks < 4; ++ks) LDB32(b[0][ks], buf, 0, ks);
    BAR(); WAIT_LGKM0();
    __builtin_amdgcn_s_setprio(1); MFMA_P(0, 0); __builtin_amdgcn_s_setprio(0);
    BAR();
    // Phase 1: read n-frag 1 (4 reads)
#pragma unroll
    for (int ks = 0; ks < 4; ++ks) LDB32(b[1][ks], buf, 1, ks);
    BAR(); WAIT_LGKM0();
    __builtin_amdgcn_s_setprio(1); MFMA_P(0, 1); __builtin_amdgcn_s_setprio(0);
    BAR();
    // Phase 2: read m-frags 2,3 (8 reads); B[buf] reads done -> stage B(t+2)
#pragma unroll
    for (int mp = 0; mp < 2; ++mp)
#pragma unroll
      for (int ks = 0; ks < 4; ++ks) LDA32(a[mp][ks], buf, 2 + mp, ks);
    if (tt + 2 < NT) { STAGE(B, buf, 0, tt + 2); STAGE(B, buf, 1, tt + 2); }
    BAR(); WAIT_LGKM0();
    __builtin_amdgcn_s_setprio(1); MFMA_P(1, 0); __builtin_amdgcn_s_setprio(0);
    BAR();
    // Phase 3: A[buf] reads done -> stage A(t+2); boundary wait
    if (tt + 2 < NT) { STAGE(A, buf, 0, tt + 2); STAGE(A, buf, 1, tt + 2); }
    BAR(); WAIT_LGKM0();
    __builtin_amdgcn_s_setprio(1); MFMA_P(1, 1); __builtin_amdgcn_s_setprio(0);
    if (tt < NT - 1) {
      if (tt + 2 < NT) { WAIT_VM8(); } else { WAIT_VM0(); }
    }
    BAR();
  }

  // ---------------- epilogue (32x32 C/D map) ----------------
  if (EPI == 0) {
    float* C = reinterpret_cast<float*>(Cout) + (size_t)bz * zstride;
    const int rb = bm * 256 + wr * 128 + 4 * (ln >> 5);
    const int cb = bn * 256 + wc * 64 + (ln & 31);
#pragma unroll
    for (int mi = 0; mi < 4; ++mi)
#pragma unroll
      for (int nh = 0; nh < 2; ++nh)
#pragma unroll
        for (int reg = 0; reg < 16; ++reg) {
          int row = rb + mi * 32 + (reg & 3) + 8 * (reg >> 2);
          C[(size_t)row * Nout + cb + nh * 32] = acc[mi][nh][reg];
        }
  } else {
    // n-frag 0 = gate (32 cols), n-frag 1 = up -> thread-local silu pairing
    unsigned short* Hm = reinterpret_cast<unsigned short*>(Cout);
    const int rb = bm * 256 + wr * 128 + 4 * (ln >> 5);
    const int cb = bn * 128 + wc * 32 + (ln & 31);
#pragma unroll
    for (int mi = 0; mi < 4; ++mi)
#pragma unroll
      for (int reg = 0; reg < 16; ++reg) {
        float gg = acc[mi][0][reg];
        float uu = acc[mi][1][reg];
        float h = gg * uu * __builtin_amdgcn_rcpf(1.0f + __expf(-gg));
        int row = rb + mi * 32 + (reg & 3) + 8 * (reg >> 2);
        Hm[(size_t)row * Nout + cb] = f32_to_bf16_rne(h);
      }
  }
}

// ---------------- host ----------------

extern "C" void kernel_launch(void* const* d_in, const int* in_sizes, int n_in,
                              void* d_out, int out_size, void* d_ws, size_t ws_size,
                              hipStream_t stream) {
  const float* x      = (const float*)d_in[0];
  const float* gate_w = (const float*)d_in[1];
  const float* up_w   = (const float*)d_in[2];
  const float* down_w = (const float*)d_in[3];
  float* y = (float*)d_out;

  const int Mtok = 4096, H = 2048, I = 8192;

  unsigned short* x_bf = (unsigned short*)d_ws;
  unsigned short* Bcat = x_bf + (size_t)Mtok * H;
  unsigned short* d_bf = Bcat + (size_t)2 * I * H;
  unsigned short* h_bf = d_bf + (size_t)H * I;
  float* part = (float*)Bcat;  // reuses Bcat region after gemm1

  prep<<<2048, 256, 0, stream>>>(x, gate_w, up_w, down_w, x_bf, d_bf, Bcat);

  // gemm1: (4096 x 2048) * (16384 x 2048)^T -> swiglu -> h_bf (4096 x 8192)
  gemm8p<1><<<dim3(1024), 512, 0, stream>>>(
      x_bf, Bcat, h_bf, H, H, H, I, 0, Mtok / 256, (2 * I) / 256);

  // gemm2: split-K=2: (4096 x 8192) * (2048 x 8192)^T -> partials
  gemm8p<0><<<dim3(256), 512, 0, stream>>>(
      h_bf, d_bf, part, I / 2, I, I, H, (size_t)Mtok * H, Mtok / 256, H / 256);

  reduce_add<<<2048, 256, 0, stream>>>(part, part + (size_t)Mtok * H, y,
                                       (Mtok * H) / 4);
}

// Round 7
// 493.430 us; speedup vs baseline: 1.0158x; 1.0158x over previous
//
#include <hip/hip_runtime.h>
#include <hip/hip_bf16.h>
#include <stdint.h>

typedef __attribute__((ext_vector_type(4))) float f32x4;
typedef __attribute__((ext_vector_type(8))) short short8;

__device__ __forceinline__ unsigned short f32_to_bf16_rne(float f) {
  union { float f; unsigned int u; } v; v.f = f;
  unsigned int u = v.u;
  unsigned int r = u + 0x7fffu + ((u >> 16) & 1u);
  return (unsigned short)(r >> 16);
}

#define GLOAD16(gp, lp)                                                 \
  __builtin_amdgcn_global_load_lds(                                     \
      (const __attribute__((address_space(1))) void*)(const void*)(gp), \
      (__attribute__((address_space(3))) void*)(void*)(lp), 16, 0, 0)

#define BAR() __builtin_amdgcn_s_barrier()
#define WAIT_LGKM0() asm volatile("s_waitcnt lgkmcnt(0)" ::: "memory")
#define WAIT_VM8() asm volatile("s_waitcnt vmcnt(8)" ::: "memory")
#define WAIT_VM0() asm volatile("s_waitcnt vmcnt(0)" ::: "memory")

// ---------------- merged converter / packer ----------------
// Segments: [0, NX4): x ; [NX4, NX4+ND4): down_w ; rest: Bcat pack.
// Bcat[16384][2048]: row R -> grp=R>>5, s=R&31; s<16: gate row grp*16+s,
// else up row grp*16+(s-16). (16-row interleave for the 16x16 MFMA pairing.)
__global__ __launch_bounds__(256) void prep(
    const float* __restrict__ x, const float* __restrict__ g,
    const float* __restrict__ u, const float* __restrict__ dw,
    unsigned short* __restrict__ x_bf, unsigned short* __restrict__ d_bf,
    unsigned short* __restrict__ Bcat) {
  const int NX4 = 2097152;   // 4096*2048/4
  const int ND4 = 4194304;   // 2048*8192/4
  const int NP4 = 8388608;   // 16384*2048/4
  const int total = NX4 + ND4 + NP4;
  int i = blockIdx.x * 256 + threadIdx.x;
  for (; i < total; i += gridDim.x * 256) {
    const float* src;
    unsigned short* dst;
    if (i < NX4) {
      src = x + ((size_t)i << 2);
      dst = x_bf + ((size_t)i << 2);
    } else if (i < NX4 + ND4) {
      int j = i - NX4;
      src = dw + ((size_t)j << 2);
      dst = d_bf + ((size_t)j << 2);
    } else {
      int j = i - NX4 - ND4;
      int R = j >> 9, h4 = j & 511;
      int grp = R >> 5, s = R & 31;
      src = (s < 16 ? g : u) + (((size_t)(grp * 16 + (s & 15))) << 11) + (h4 << 2);
      dst = Bcat + ((size_t)j << 2);
    }
    float4 v = *reinterpret_cast<const float4*>(src);
    ushort4 o;
    o.x = f32_to_bf16_rne(v.x);
    o.y = f32_to_bf16_rne(v.y);
    o.z = f32_to_bf16_rne(v.z);
    o.w = f32_to_bf16_rne(v.w);
    *reinterpret_cast<ushort4*>(dst) = o;
  }
}

__global__ __launch_bounds__(256) void reduce_add(const float* __restrict__ a,
                                                  const float* __restrict__ b,
                                                  float* __restrict__ o, int n4) {
  int i = blockIdx.x * 256 + threadIdx.x;
  for (; i < n4; i += gridDim.x * 256) {
    float4 x = reinterpret_cast<const float4*>(a)[i];
    float4 y = reinterpret_cast<const float4*>(b)[i];
    float4 z;
    z.x = x.x + y.x; z.y = x.y + y.y; z.z = x.z + y.z; z.w = x.w + y.w;
    reinterpret_cast<float4*>(o)[i] = z;
  }
}

// ------- persistent 256x256x64 8-phase GEMM, continuous pipeline ---------
// C = A(M x K) * B(N x K)^T, bf16 K-major. 8 waves, wave tile 128x64,
// 16x16x32 MFMA. Block processes tpb consecutive tiles as ONE flattened
// K-step stream (total = tpb*NT): the in-loop t+2 staging continues across
// output-tile boundaries (stage-side bases advance 2 K-steps early), the
// boundary wait stays vmcnt(8) (never drains), and epilogue stores get a
// full K-tile of slack before the next vmcnt(8) retires them.

#define MFMA_Q(MH, NH)                                                        \
  do {                                                                        \
    _Pragma("unroll") for (int kh = 0; kh < 2; ++kh) {                        \
      _Pragma("unroll") for (int mi = 0; mi < 4; ++mi) {                      \
        _Pragma("unroll") for (int ni = 0; ni < 2; ++ni) {                    \
          acc[(MH)*4 + mi][(NH)*2 + ni] =                                     \
              __builtin_amdgcn_mfma_f32_16x16x32_bf16(                        \
                  a[mi][kh], b[(NH)*2 + ni][kh],                              \
                  acc[(MH)*4 + mi][(NH)*2 + ni], 0, 0, 0);                    \
        }                                                                     \
      }                                                                       \
    }                                                                         \
  } while (0)

#define STAGEA(BUF, H, T)                                                     \
  do {                                                                        \
    const unsigned short* p0_ =                                               \
        sAb + (size_t)((H)*128 + r0) * ldA + (size_t)(T)*64 + c0;             \
    const unsigned short* p1_ =                                               \
        sAb + (size_t)((H)*128 + r1) * ldA + (size_t)(T)*64 + c1;             \
    GLOAD16(p0_, &sA[BUF][H][off0 >> 1]);                                     \
    GLOAD16(p1_, &sA[BUF][H][(off0 >> 1) + 512]);                             \
  } while (0)

#define STAGEB(BUF, H, T)                                                     \
  do {                                                                        \
    const unsigned short* p0_ =                                               \
        sBb + (size_t)((H)*128 + r0) * ldB + (size_t)(T)*64 + c0;             \
    const unsigned short* p1_ =                                               \
        sBb + (size_t)((H)*128 + r1) * ldB + (size_t)(T)*64 + c1;             \
    GLOAD16(p0_, &sB[BUF][H][off0 >> 1]);                                     \
    GLOAD16(p1_, &sB[BUF][H][(off0 >> 1) + 512]);                             \
  } while (0)

#define LDA(dst, BUF, MI, KH)                                                 \
  {                                                                           \
    int lb_ = ((MI)*16 + frow) * 128 + (KH)*64 + kg * 16;                     \
    int ph_ = lb_ ^ ((frow & 7) << 4);                                        \
    dst = *reinterpret_cast<const short8*>(                                   \
        reinterpret_cast<const char*>(&sA[BUF][wr][0]) + ph_);                \
  }

#define LDB(dst, BUF, NI, KH)                                                 \
  {                                                                           \
    int lb_ = ((wc & 1) * 64 + (NI)*16 + frow) * 128 + (KH)*64 + kg * 16;     \
    int ph_ = lb_ ^ ((frow & 7) << 4);                                        \
    dst = *reinterpret_cast<const short8*>(                                   \
        reinterpret_cast<const char*>(&sB[BUF][wc >> 1][0]) + ph_);           \
  }

template <int EPI>
__global__ __launch_bounds__(512, 2) void gemm8p(
    const unsigned short* __restrict__ A, const unsigned short* __restrict__ B,
    void* __restrict__ Cout, int K, int ldA, int ldB, int Nout, size_t zstride,
    int nbm, int nbn, int tpb) {
  __shared__ unsigned short sA[2][2][128 * 64];
  __shared__ unsigned short sB[2][2][128 * 64];

  const int t = threadIdx.x;
  const int wv = t >> 6, ln = t & 63;
  const int wr = wv >> 2, wc = wv & 3;
  const int frow = ln & 15, kg = ln >> 4;

  // bijective XCD swizzle (gridDim.x % 8 == 0)
  const int r = blockIdx.x;
  const int lin = (r & 7) * (gridDim.x >> 3) + (r >> 3);
  const int g0 = lin * tpb;

  const int off0 = wv * 2048 + ln * 16;
  const int off1 = off0 + 1024;
  const int s0 = off0 ^ (((off0 >> 7) & 7) << 4);
  const int s1 = off1 ^ (((off1 >> 7) & 7) << 4);
  const int r0 = s0 >> 7, c0 = (s0 & 127) >> 1;
  const int r1 = s1 >> 7, c1 = (s1 & 127) >> 1;

  // compute-side tile coords
  int cg = g0;
  int cbm = cg % nbm, crest = cg / nbm, cbn = crest % nbn, cbz = crest / nbn;

  // stage-side bases (advance 2 K-steps ahead of compute)
  const unsigned short* sAb = A + (size_t)cbz * K + (size_t)(cbm * 256) * ldA;
  const unsigned short* sBb = B + (size_t)cbz * K + (size_t)(cbn * 256) * ldB;
  int sg = cg;

  f32x4 acc[8][4] = {};
  short8 a[4][2], b[4][2];

  const int NT = K >> 6;        // K-steps per tile (>= 2)
  const int total = tpb * NT;   // flattened K-steps for this block
  int sk = 2, qs = 2;           // next K-step to stage (within tile sg)
  int ck = 0;                   // K-step within compute tile

  // Prologue: stage K-steps 0 and 1 of tile g0 (16 loads); vmcnt(8) -> step0.
  STAGEA(0, 0, 0); STAGEA(0, 1, 0);
  STAGEB(0, 0, 0); STAGEB(0, 1, 0);
  STAGEA(1, 0, 1); STAGEA(1, 1, 1);
  STAGEB(1, 0, 1); STAGEB(1, 1, 1);
  WAIT_VM8();
  BAR();

  for (int q = 0; q < total; ++q) {
    const int buf = q & 1;
    const bool st = (qs < total);
    if (st && sk == NT) {  // stage side crosses into the next output tile
      sk = 0; ++sg;
      int sbm = sg % nbm, srest = sg / nbm, sbn = srest % nbn, sbz = srest / nbn;
      sAb = A + (size_t)sbz * K + (size_t)(sbm * 256) * ldA;
      sBb = B + (size_t)sbz * K + (size_t)(sbn * 256) * ldB;
    }
    // Phase 0: read a(m-lo) both halves, b(n-lo) both halves
#pragma unroll
    for (int mi = 0; mi < 4; ++mi) { LDA(a[mi][0], buf, mi, 0); LDA(a[mi][1], buf, mi, 1); }
#pragma unroll
    for (int ni = 0; ni < 2; ++ni) { LDB(b[ni][0], buf, ni, 0); LDB(b[ni][1], buf, ni, 1); }
    BAR(); WAIT_LGKM0();
    __builtin_amdgcn_s_setprio(1); MFMA_Q(0, 0); __builtin_amdgcn_s_setprio(0);
    BAR();
    // Phase 1: read b(n-hi)
#pragma unroll
    for (int ni = 2; ni < 4; ++ni) { LDB(b[ni][0], buf, ni, 0); LDB(b[ni][1], buf, ni, 1); }
    BAR(); WAIT_LGKM0();
    __builtin_amdgcn_s_setprio(1); MFMA_Q(0, 1); __builtin_amdgcn_s_setprio(0);
    BAR();
    // Phase 2: read a(m-hi); B[buf] reads done -> stage B(q+2)
#pragma unroll
    for (int mi = 0; mi < 4; ++mi) { LDA(a[mi][0], buf, mi + 4, 0); LDA(a[mi][1], buf, mi + 4, 1); }
    if (st) { STAGEB(buf, 0, sk); STAGEB(buf, 1, sk); }
    BAR(); WAIT_LGKM0();
    __builtin_amdgcn_s_setprio(1); MFMA_Q(1, 0); __builtin_amdgcn_s_setprio(0);
    BAR();
    // Phase 3: A[buf] reads done -> stage A(q+2); boundary wait
    if (st) { STAGEA(buf, 0, sk); STAGEA(buf, 1, sk); ++sk; ++qs; }
    BAR(); WAIT_LGKM0();
    __builtin_amdgcn_s_setprio(1); MFMA_Q(1, 1); __builtin_amdgcn_s_setprio(0);
    if (q == total - 2) { WAIT_VM0(); } else if (q < total - 1) { WAIT_VM8(); }
    BAR();

    // ---------------- per-tile epilogue ----------------
    if (++ck == NT) {
      if (EPI == 0) {
        float* C = reinterpret_cast<float*>(Cout) + (size_t)cbz * zstride;
        const int rb = cbm * 256 + wr * 128 + kg * 4;
        const int cb = cbn * 256 + wc * 64 + frow;
#pragma unroll
        for (int mi = 0; mi < 8; ++mi)
#pragma unroll
          for (int ni = 0; ni < 4; ++ni)
#pragma unroll
            for (int j = 0; j < 4; ++j)
              C[(size_t)(rb + mi * 16 + j) * Nout + (cb + ni * 16)] = acc[mi][ni][j];
      } else {
        unsigned short* Hm = reinterpret_cast<unsigned short*>(Cout);
        const int rb = cbm * 256 + wr * 128 + kg * 4;
        const int cb = cbn * 128 + wc * 32 + frow;
#pragma unroll
        for (int mi = 0; mi < 8; ++mi)
#pragma unroll
          for (int p = 0; p < 2; ++p)
#pragma unroll
            for (int j = 0; j < 4; ++j) {
              float gg = acc[mi][2 * p][j];
              float uu = acc[mi][2 * p + 1][j];
              float h = gg * uu * __builtin_amdgcn_rcpf(1.0f + __expf(-gg));
              Hm[(size_t)(rb + mi * 16 + j) * Nout + (cb + p * 16)] = f32_to_bf16_rne(h);
            }
      }
      if (q + 1 < total) {
        ck = 0; ++cg;
        cbm = cg % nbm; crest = cg / nbm; cbn = crest % nbn; cbz = crest / nbn;
#pragma unroll
        for (int mi = 0; mi < 8; ++mi)
#pragma unroll
          for (int ni = 0; ni < 4; ++ni)
            acc[mi][ni] = (f32x4){0.f, 0.f, 0.f, 0.f};
      }
    }
  }
}

// ---------------- host ----------------

extern "C" void kernel_launch(void* const* d_in, const int* in_sizes, int n_in,
                              void* d_out, int out_size, void* d_ws, size_t ws_size,
                              hipStream_t stream) {
  const float* x      = (const float*)d_in[0];
  const float* gate_w = (const float*)d_in[1];
  const float* up_w   = (const float*)d_in[2];
  const float* down_w = (const float*)d_in[3];
  float* y = (float*)d_out;

  const int Mtok = 4096, H = 2048, I = 8192;

  unsigned short* x_bf = (unsigned short*)d_ws;
  unsigned short* Bcat = x_bf + (size_t)Mtok * H;
  unsigned short* d_bf = Bcat + (size_t)2 * I * H;
  unsigned short* h_bf = d_bf + (size_t)H * I;
  float* part = (float*)Bcat;  // reuses Bcat region after gemm1

  prep<<<2048, 256, 0, stream>>>(x, gate_w, up_w, down_w, x_bf, d_bf, Bcat);

  // gemm1: persistent tpb=4, 256 blocks (bm-fastest: 4 tiles share one B-panel)
  gemm8p<1><<<dim3(256), 512, 0, stream>>>(
      x_bf, Bcat, h_bf, H, H, H, I, 0, Mtok / 256, (2 * I) / 256, 4);

  // gemm2: split-K=2, 256 blocks, tpb=1 (identical to the verified R5 path)
  gemm8p<0><<<dim3(256), 512, 0, stream>>>(
      h_bf, d_bf, part, I / 2, I, I, H, (size_t)Mtok * H, Mtok / 256, H / 256, 1);

  reduce_add<<<2048, 256, 0, stream>>>(part, part + (size_t)Mtok * H, y,
                                       (Mtok * H) / 4);
}